// Round 3
// baseline (1213.557 us; speedup 1.0000x reference)
//
#include <hip/hip_runtime.h>
#include <hip/hip_bf16.h>

#define NR 12288
#define DIMS 256
#define NCHUNK 8
#define CW (NR / NCHUNK)   // 1536
#define BM 64
#define TOPP 9

typedef __attribute__((ext_vector_type(8))) short short8v;
typedef __attribute__((ext_vector_type(4))) float f32x4;

__device__ __forceinline__ unsigned short f2bf(float f) {
    unsigned int u = __float_as_uint(f);
    u += 0x7fffu + ((u >> 16) & 1u);   // round-to-nearest-even
    return (unsigned short)(u >> 16);
}

// Maintain the 9 largest seen. Static indexing only (rule #20).
__device__ __forceinline__ void top9_insert(float (&a)[9], float& mn, float v) {
    if (v > mn) {
        bool done = false;
#pragma unroll
        for (int k = 0; k < 9; ++k) {
            bool hit = (!done) && (a[k] == mn);
            if (hit) a[k] = v;
            done = done || hit;
        }
        float m = a[0];
#pragma unroll
        for (int k = 1; k < 9; ++k) m = fminf(m, a[k]);
        mn = m;
    }
}

// ---------- 1) row-normalize fp32 -> bf16, one row per wave ----------
__global__ void k_norm(const float* __restrict__ x, unsigned short* __restrict__ emb) {
    const int wave = threadIdx.x >> 6, lane = threadIdx.x & 63;
    const int row = blockIdx.x * 4 + wave;
    const float4 v = *(const float4*)(x + (size_t)row * DIMS + lane * 4);
    float ss = v.x * v.x + v.y * v.y + v.z * v.z + v.w * v.w;
#pragma unroll
    for (int off = 32; off > 0; off >>= 1) ss += __shfl_xor(ss, off);
    const float inv = 1.0f / fmaxf(sqrtf(ss), 1e-12f);
    ushort4 o;
    o.x = f2bf(v.x * inv); o.y = f2bf(v.y * inv);
    o.z = f2bf(v.z * inv); o.w = f2bf(v.w * inv);
    *(ushort4*)(emb + (size_t)row * DIMS + lane * 4) = o;
}

// Shared GEMM micro-tile: 16 rows x 64 cols per wave-iteration, 4 independent
// acc chains. K-order per chain is fixed (kk=0..7) -> bit-identical sim in
// both passes regardless of scheduling.
#define GEMM_TILE4(B0, B1, B2, B3)                                            \
    f32x4 acc0 = {0.f, 0.f, 0.f, 0.f}, acc1 = {0.f, 0.f, 0.f, 0.f},           \
          acc2 = {0.f, 0.f, 0.f, 0.f}, acc3 = {0.f, 0.f, 0.f, 0.f};           \
    _Pragma("unroll")                                                          \
    for (int kk = 0; kk < 8; ++kk) {                                           \
        short8v bF0 = *(const short8v*)(B0 + kk * 32);                         \
        short8v bF1 = *(const short8v*)(B1 + kk * 32);                         \
        short8v bF2 = *(const short8v*)(B2 + kk * 32);                         \
        short8v bF3 = *(const short8v*)(B3 + kk * 32);                         \
        acc0 = __builtin_amdgcn_mfma_f32_16x16x32_bf16(aF[kk], bF0, acc0, 0, 0, 0); \
        acc1 = __builtin_amdgcn_mfma_f32_16x16x32_bf16(aF[kk], bF1, acc1, 0, 0, 0); \
        acc2 = __builtin_amdgcn_mfma_f32_16x16x32_bf16(aF[kk], bF2, acc2, 0, 0, 0); \
        acc3 = __builtin_amdgcn_mfma_f32_16x16x32_bf16(aF[kk], bF3, acc3, 0, 0, 0); \
    }

// ---------- 2) GEMM pass 1: per-row top-9 over a column chunk ----------
// __launch_bounds__(256,4): VGPR cap 128 so t9[4][9]+aF[8]+accs stay in
// registers (round-2 profile: cap 64 -> scratch spill, all pipes idle).
__global__ __launch_bounds__(256, 4) void k_pass1(const unsigned short* __restrict__ emb,
                                                  float* __restrict__ t9p) {
    const int bid = blockIdx.x;
    const int chunk = bid & 7, rb = bid >> 3;        // chunk -> XCD locality
    const int wave = threadIdx.x >> 6, lane = threadIdx.x & 63;
    const int l15 = lane & 15, lg = lane >> 4;
    const int R0 = rb * BM + wave * 16;

    short8v aF[8];
    const unsigned short* abase = emb + (size_t)(R0 + l15) * DIMS + lg * 8;
#pragma unroll
    for (int kk = 0; kk < 8; ++kk) aF[kk] = *(const short8v*)(abase + kk * 32);

    float t9[4][9];
    float tmin[4];
#pragma unroll
    for (int r = 0; r < 4; ++r) {
        tmin[r] = -3e38f;
#pragma unroll
        for (int k = 0; k < 9; ++k) t9[r][k] = -3e38f;
    }

    const int Cb = chunk * CW;
    const unsigned short* bbase = emb + (size_t)(Cb + l15) * DIMS + lg * 8;
    for (int ct = 0; ct < CW / 64; ++ct) {
        const unsigned short* b0 = bbase + (size_t)(ct * 64) * DIMS;
        const unsigned short* b1 = b0 + 16 * DIMS;
        const unsigned short* b2 = b0 + 32 * DIMS;
        const unsigned short* b3 = b0 + 48 * DIMS;
        GEMM_TILE4(b0, b1, b2, b3)
#pragma unroll
        for (int r = 0; r < 4; ++r) {
            top9_insert(t9[r], tmin[r], acc0[r]);
            top9_insert(t9[r], tmin[r], acc1[r]);
            top9_insert(t9[r], tmin[r], acc2[r]);
            top9_insert(t9[r], tmin[r], acc3[r]);
        }
    }

    // Exact merge across the 16 lanes sharing each row: butterfly over l15.
    // Snapshot partner's 9 values BEFORE inserting (both sides mutate in
    // lockstep; interleaving shuffle+insert would read partner mid-mutation).
#pragma unroll
    for (int off = 1; off < 16; off <<= 1) {
#pragma unroll
        for (int r = 0; r < 4; ++r) {
            float o[9];
#pragma unroll
            for (int k = 0; k < 9; ++k) o[k] = __shfl_xor(t9[r][k], off);
#pragma unroll
            for (int k = 0; k < 9; ++k) top9_insert(t9[r], tmin[r], o[k]);
        }
    }

    if (l15 == 0) {
        // every lane in the 16-group now holds the exact row top-9
#pragma unroll
        for (int r = 0; r < 4; ++r) {
            float* dst = t9p + ((size_t)(R0 + lg * 4 + r) * NCHUNK + chunk) * TOPP;
#pragma unroll
            for (int k = 0; k < 9; ++k) dst[k] = t9[r][k];
        }
    }
}

// ---------- 3) merge chunk top-9s -> per-row threshold (9th largest) ----------
__global__ void k_thr(const float* __restrict__ t9p, float* __restrict__ thr) {
    const int row = blockIdx.x * 256 + threadIdx.x;
    float best[9], bmin = -3e38f;
#pragma unroll
    for (int k = 0; k < 9; ++k) best[k] = -3e38f;
    const float* src = t9p + (size_t)row * NCHUNK * TOPP;
    for (int c = 0; c < NCHUNK * TOPP; ++c) top9_insert(best, bmin, src[c]);
    thr[row] = bmin;
}

// ---------- 4) GEMM pass 2 (bit-identical sim): out-deg + in-deg counts ----------
__global__ __launch_bounds__(256, 4) void k_pass2(const unsigned short* __restrict__ emb,
                                                  const float* __restrict__ thr,
                                                  unsigned* __restrict__ dd,
                                                  unsigned* __restrict__ gg) {
    const int bid = blockIdx.x;
    const int chunk = bid & 7, rb = bid >> 3;
    const int wave = threadIdx.x >> 6, lane = threadIdx.x & 63;
    const int l15 = lane & 15, lg = lane >> 4;
    const int R0 = rb * BM + wave * 16;

    __shared__ unsigned colcnt[CW];     // 6 KB: in-degree counts for this chunk
    __shared__ unsigned degp[BM];       // out-degree counts for this block's rows
    for (int i = threadIdx.x; i < CW; i += 256) colcnt[i] = 0;
    if (threadIdx.x < BM) degp[threadIdx.x] = 0;
    __syncthreads();

    short8v aF[8];
    const unsigned short* abase = emb + (size_t)(R0 + l15) * DIMS + lg * 8;
#pragma unroll
    for (int kk = 0; kk < 8; ++kk) aF[kk] = *(const short8v*)(abase + kk * 32);

    float thrv[4];
#pragma unroll
    for (int r = 0; r < 4; ++r) thrv[r] = thr[R0 + lg * 4 + r];

    const int Cb = chunk * CW;
    const unsigned short* bbase = emb + (size_t)(Cb + l15) * DIMS + lg * 8;
    for (int ct = 0; ct < CW / 64; ++ct) {
        const unsigned short* b0 = bbase + (size_t)(ct * 64) * DIMS;
        const unsigned short* b1 = b0 + 16 * DIMS;
        const unsigned short* b2 = b0 + 32 * DIMS;
        const unsigned short* b3 = b0 + 48 * DIMS;
        GEMM_TILE4(b0, b1, b2, b3)
        const int rloc = wave * 16 + lg * 4;
        const int cloc = ct * 64 + l15;
#pragma unroll
        for (int r = 0; r < 4; ++r) {
            const int rg = R0 + lg * 4 + r;
            if (acc0[r] >= thrv[r] && (Cb + cloc)      != rg) { atomicAdd(&degp[rloc + r], 1u); atomicAdd(&colcnt[cloc],      1u); }
            if (acc1[r] >= thrv[r] && (Cb + cloc + 16) != rg) { atomicAdd(&degp[rloc + r], 1u); atomicAdd(&colcnt[cloc + 16], 1u); }
            if (acc2[r] >= thrv[r] && (Cb + cloc + 32) != rg) { atomicAdd(&degp[rloc + r], 1u); atomicAdd(&colcnt[cloc + 32], 1u); }
            if (acc3[r] >= thrv[r] && (Cb + cloc + 48) != rg) { atomicAdd(&degp[rloc + r], 1u); atomicAdd(&colcnt[cloc + 48], 1u); }
        }
    }
    __syncthreads();
    if (threadIdx.x < BM) {
        unsigned c = degp[threadIdx.x];
        if (c) atomicAdd(&dd[rb * BM + threadIdx.x], c);
    }
    for (int i = threadIdx.x; i < CW; i += 256) {
        unsigned c = colcnt[i];
        if (c) atomicAdd(&gg[Cb + i], c);
    }
}

// ---------- 5) wsum = sum_i o*d + g*d - 2o, d = max(o,1)  (integer, determ.) ----------
__global__ void k_wsum(const unsigned* __restrict__ dd, const unsigned* __restrict__ gg,
                       unsigned long long* __restrict__ wsum) {
    const int i = blockIdx.x * 256 + threadIdx.x;
    const unsigned long long o = dd[i];
    const unsigned long long g = gg[i];
    const unsigned long long d = o ? o : 1ull;
    unsigned long long acc = o * d + g * d - 2ull * o;
#pragma unroll
    for (int off = 32; off > 0; off >>= 1) acc += __shfl_xor(acc, off);
    if ((threadIdx.x & 63) == 0 && acc) atomicAdd(wsum, acc);
}

// ---------- 6) finalize ----------
__global__ void k_fin(const unsigned long long* __restrict__ wsum, float* __restrict__ out) {
    out[0] = (float)((double)*wsum * (0.01 / ((double)NR * (double)NR)));
}

extern "C" void kernel_launch(void* const* d_in, const int* in_sizes, int n_in,
                              void* d_out, int out_size, void* d_ws, size_t ws_size,
                              hipStream_t stream) {
    const float* x = (const float*)d_in[0];
    float* out = (float*)d_out;
    char* ws = (char*)d_ws;

    size_t off = 0;
    unsigned short* emb = (unsigned short*)(ws + off); off += (size_t)NR * DIMS * 2;         // 6.29 MB
    float* t9p = (float*)(ws + off);                  off += (size_t)NR * NCHUNK * TOPP * 4; // 3.54 MB
    float* thr = (float*)(ws + off);                  off += (size_t)NR * 4;
    unsigned* dd = (unsigned*)(ws + off);             off += (size_t)NR * 4;
    unsigned* gg = (unsigned*)(ws + off);             off += (size_t)NR * 4;
    unsigned long long* wsum = (unsigned long long*)(ws + off);

    hipMemsetAsync(dd, 0, (size_t)NR * 4, stream);
    hipMemsetAsync(gg, 0, (size_t)NR * 4, stream);
    hipMemsetAsync(wsum, 0, 8, stream);

    k_norm<<<NR / 4, 256, 0, stream>>>(x, emb);
    k_pass1<<<NR / BM * NCHUNK, 256, 0, stream>>>(emb, t9p);
    k_thr<<<NR / 256, 256, 0, stream>>>(t9p, thr);
    k_pass2<<<NR / BM * NCHUNK, 256, 0, stream>>>(emb, thr, dd, gg);
    k_wsum<<<NR / 256, 256, 0, stream>>>(dd, gg, wsum);
    k_fin<<<1, 1, 0, stream>>>(wsum, out);
}

// Round 4
// 1139.530 us; speedup vs baseline: 1.0650x; 1.0650x over previous
//
#include <hip/hip_runtime.h>
#include <hip/hip_bf16.h>

#define NR 12288
#define DIMS 256
#define RB 512              // row bytes = DIMS * 2 (bf16)
#define NCH1 8
#define CW1 (NR / NCH1)     // 1536
#define NCH2 16
#define CW2 (NR / NCH2)     // 768
#define TOPP 9

typedef __attribute__((ext_vector_type(8))) short short8v;
typedef __attribute__((ext_vector_type(4))) float f32x4;

__device__ __forceinline__ unsigned short f2bf(float f) {
    unsigned int u = __float_as_uint(f);
    u += 0x7fffu + ((u >> 16) & 1u);   // round-to-nearest-even
    return (unsigned short)(u >> 16);
}

// Maintain the 9 largest seen. Static indexing only (rule #20).
__device__ __forceinline__ void top9_insert(float (&a)[9], float& mn, float v) {
    if (v > mn) {
        bool done = false;
#pragma unroll
        for (int k = 0; k < 9; ++k) {
            bool hit = (!done) && (a[k] == mn);
            if (hit) a[k] = v;
            done = done || hit;
        }
        float m = a[0];
#pragma unroll
        for (int k = 1; k < 9; ++k) m = fminf(m, a[k]);
        mn = m;
    }
}

// ---------- 1) row-normalize fp32 -> bf16, one row per wave ----------
__global__ void k_norm(const float* __restrict__ x, unsigned short* __restrict__ emb) {
    const int wave = threadIdx.x >> 6, lane = threadIdx.x & 63;
    const int row = blockIdx.x * 4 + wave;
    const float4 v = *(const float4*)(x + (size_t)row * DIMS + lane * 4);
    float ss = v.x * v.x + v.y * v.y + v.z * v.z + v.w * v.w;
#pragma unroll
    for (int off = 32; off > 0; off >>= 1) ss += __shfl_xor(ss, off);
    const float inv = 1.0f / fmaxf(sqrtf(ss), 1e-12f);
    ushort4 o;
    o.x = f2bf(v.x * inv); o.y = f2bf(v.y * inv);
    o.z = f2bf(v.z * inv); o.w = f2bf(v.w * inv);
    *(ushort4*)(emb + (size_t)row * DIMS + lane * 4) = o;
}

// Half-K tile in LDS: 64 cols x 128 K = 64 x 256B = 16 KB.
// Linear tile byte b: col = b>>8, within = b&255. Stored at b ^ ((col&7)<<4)
// (XOR bits 4-6) so that fragment reads (16 lanes same k-slice, cols 0..15)
// spread over all 32 banks (8-round minimum for a wave64 b128 read).
__device__ __forceinline__ const short8v* frag_ptr(const char* buf, int col, int kkl, int lg) {
    const int b = (col << 8) + (kkl << 6) + (lg << 4);
    return (const short8v*)(buf + (b ^ ((col & 7) << 4)));
}

// Staging (reg-staged, plain HIP): thread t covers tile bytes
// {r*4096 + t*16, r=0..3}; col_r = r*16 + (t>>4), within = (t&15)*16.
// Global loads coalesced (4 cols x 256B contiguous per wave-round);
// ds_write applies the same XOR swizzle (r*16 doesn't change col&7).
#define STAGE_LOAD(CT, HOFF)                                                   \
    {                                                                          \
        const char* p_ = embB + (size_t)(Cb + (CT) * 64 + colA) * RB + (HOFF) + win; \
        g0 = *(const uint4*)(p_);                                              \
        g1 = *(const uint4*)(p_ + 16 * RB);                                    \
        g2 = *(const uint4*)(p_ + 32 * RB);                                    \
        g3 = *(const uint4*)(p_ + 48 * RB);                                    \
    }

#define STAGE_WRITE(SB)                                                        \
    {                                                                          \
        char* d_ = (SB) + colA * 256 + (win ^ swzA);                           \
        *(uint4*)(d_ + 0)     = g0;                                            \
        *(uint4*)(d_ + 4096)  = g1;                                            \
        *(uint4*)(d_ + 8192)  = g2;                                            \
        *(uint4*)(d_ + 12288) = g3;                                            \
    }

// ---------- 2) GEMM pass 1: per-row top-9 over a column chunk ----------
// Block: 64 rows x full chunk; 4 waves split rows (16 rows/wave, t9 = 40 regs,
// per-lane stream length 96 -> ~31% insert rate). B staged in LDS, dbuf.
__global__ __launch_bounds__(256, 4) void k_pass1(const unsigned short* __restrict__ emb,
                                                  float* __restrict__ t9p) {
    const int bid = blockIdx.x;
    const int chunk = bid & 7, rb = bid >> 3;      // chunk == XCD id (bid%8)
    const int w = threadIdx.x >> 6, lane = threadIdx.x & 63;
    const int l15 = lane & 15, lg = lane >> 4;
    const int R0 = rb * 64 + w * 16;
    const int Cb = chunk * CW1;
    const char* embB = (const char*)emb;
    const int colA = threadIdx.x >> 4;             // staging col (round 0)
    const int win = (threadIdx.x & 15) * 16;
    const int swzA = (colA & 7) << 4;

    __shared__ __align__(1024) char sb0[16384];
    __shared__ __align__(1024) char sb1[16384];

    // A fragments: 16 rows x 256 K in registers (one-time scattered load).
    short8v aF[8];
    const unsigned short* ab = emb + (size_t)(R0 + l15) * DIMS + lg * 8;
#pragma unroll
    for (int kk = 0; kk < 8; ++kk) aF[kk] = *(const short8v*)(ab + kk * 32);

    float t9[4][9]; float tmin[4];
#pragma unroll
    for (int r = 0; r < 4; ++r) {
        tmin[r] = -3e38f;
#pragma unroll
        for (int k = 0; k < 9; ++k) t9[r][k] = -3e38f;
    }

    uint4 g0, g1, g2, g3;
    // prologue: stage unit 0 (ct=0, K-half 0) into sb0
    STAGE_LOAD(0, 0)
    STAGE_WRITE(sb0)
    __syncthreads();

    f32x4 acc0, acc1, acc2, acc3;
    const int NCT = CW1 / 64;      // 24 col-tiles, 48 units
    for (int u = 0; u < 2 * NCT; ++u) {
        const int ctN = (u + 1) >> 1, hN = (u + 1) & 1;
        const bool more = (u + 1 < 2 * NCT);
        if (more) STAGE_LOAD(ctN, hN * 256)        // issue next-unit loads early
        if ((u & 1) == 0) {
            acc0 = {0.f,0.f,0.f,0.f}; acc1 = {0.f,0.f,0.f,0.f};
            acc2 = {0.f,0.f,0.f,0.f}; acc3 = {0.f,0.f,0.f,0.f};
#pragma unroll
            for (int kkl = 0; kkl < 4; ++kkl) {    // K 0..127 from sb0
                short8v b0 = *frag_ptr(sb0,      l15, kkl, lg);
                short8v b1 = *frag_ptr(sb0, 16 + l15, kkl, lg);
                short8v b2 = *frag_ptr(sb0, 32 + l15, kkl, lg);
                short8v b3 = *frag_ptr(sb0, 48 + l15, kkl, lg);
                acc0 = __builtin_amdgcn_mfma_f32_16x16x32_bf16(aF[kkl], b0, acc0, 0,0,0);
                acc1 = __builtin_amdgcn_mfma_f32_16x16x32_bf16(aF[kkl], b1, acc1, 0,0,0);
                acc2 = __builtin_amdgcn_mfma_f32_16x16x32_bf16(aF[kkl], b2, acc2, 0,0,0);
                acc3 = __builtin_amdgcn_mfma_f32_16x16x32_bf16(aF[kkl], b3, acc3, 0,0,0);
            }
        } else {
#pragma unroll
            for (int kkl = 0; kkl < 4; ++kkl) {    // K 128..255 from sb1
                short8v b0 = *frag_ptr(sb1,      l15, kkl, lg);
                short8v b1 = *frag_ptr(sb1, 16 + l15, kkl, lg);
                short8v b2 = *frag_ptr(sb1, 32 + l15, kkl, lg);
                short8v b3 = *frag_ptr(sb1, 48 + l15, kkl, lg);
                acc0 = __builtin_amdgcn_mfma_f32_16x16x32_bf16(aF[4+kkl], b0, acc0, 0,0,0);
                acc1 = __builtin_amdgcn_mfma_f32_16x16x32_bf16(aF[4+kkl], b1, acc1, 0,0,0);
                acc2 = __builtin_amdgcn_mfma_f32_16x16x32_bf16(aF[4+kkl], b2, acc2, 0,0,0);
                acc3 = __builtin_amdgcn_mfma_f32_16x16x32_bf16(aF[4+kkl], b3, acc3, 0,0,0);
            }
#pragma unroll
            for (int r = 0; r < 4; ++r) {
                top9_insert(t9[r], tmin[r], acc0[r]);
                top9_insert(t9[r], tmin[r], acc1[r]);
                top9_insert(t9[r], tmin[r], acc2[r]);
                top9_insert(t9[r], tmin[r], acc3[r]);
            }
        }
        if (more) {
            if (hN) STAGE_WRITE(sb1) else STAGE_WRITE(sb0)
        }
        __syncthreads();
    }

    // exact merge across the 16 lanes sharing each row (snapshot-then-insert)
#pragma unroll
    for (int off = 1; off < 16; off <<= 1) {
#pragma unroll
        for (int r = 0; r < 4; ++r) {
            float o[9];
#pragma unroll
            for (int k = 0; k < 9; ++k) o[k] = __shfl_xor(t9[r][k], off);
#pragma unroll
            for (int k = 0; k < 9; ++k) top9_insert(t9[r], tmin[r], o[k]);
        }
    }
    if (l15 == 0) {
#pragma unroll
        for (int r = 0; r < 4; ++r) {
            float* dst = t9p + ((size_t)(R0 + lg * 4 + r) * NCH1 + chunk) * TOPP;
#pragma unroll
            for (int k = 0; k < 9; ++k) dst[k] = t9[r][k];
        }
    }
}

// ---------- 3) merge chunk top-9s -> per-row threshold (9th largest) ----------
__global__ void k_thr(const float* __restrict__ t9p, float* __restrict__ thr) {
    const int row = blockIdx.x * 256 + threadIdx.x;
    float best[9], bmin = -3e38f;
#pragma unroll
    for (int k = 0; k < 9; ++k) best[k] = -3e38f;
    const float* src = t9p + (size_t)row * NCH1 * TOPP;
    for (int c = 0; c < NCH1 * TOPP; ++c) top9_insert(best, bmin, src[c]);
    thr[row] = bmin;
}

// ---------- 4) GEMM pass 2 (bit-identical sim): out-deg + in-deg counts ----------
// Block: 64 rows; waves split cols (16-col strip each) -> MFMA:ds_read = 4:1.
__global__ __launch_bounds__(256, 4) void k_pass2(const unsigned short* __restrict__ emb,
                                                  const float* __restrict__ thr,
                                                  unsigned* __restrict__ dd,
                                                  unsigned* __restrict__ gg) {
    const int bid = blockIdx.x;
    const int chunk = bid & 15, rb = bid >> 4;
    const int w = threadIdx.x >> 6, lane = threadIdx.x & 63;
    const int l15 = lane & 15, lg = lane >> 4;
    const int R0 = rb * 64;
    const int Cb = chunk * CW2;
    const char* embB = (const char*)emb;
    const int colA = threadIdx.x >> 4;
    const int win = (threadIdx.x & 15) * 16;
    const int swzA = (colA & 7) << 4;

    __shared__ __align__(1024) char sb0[16384];
    __shared__ __align__(1024) char sb1[16384];
    __shared__ unsigned colcnt[CW2];   // 3 KB in-degree counts
    for (int i = threadIdx.x; i < CW2; i += 256) colcnt[i] = 0;

    // A fragments: 64 rows (4 tiles of 16) x 256 K
    short8v aF0[8], aF1[8], aF2[8], aF3[8];
    {
        const unsigned short* a0 = emb + (size_t)(R0 +  0 + l15) * DIMS + lg * 8;
        const unsigned short* a1 = emb + (size_t)(R0 + 16 + l15) * DIMS + lg * 8;
        const unsigned short* a2 = emb + (size_t)(R0 + 32 + l15) * DIMS + lg * 8;
        const unsigned short* a3 = emb + (size_t)(R0 + 48 + l15) * DIMS + lg * 8;
#pragma unroll
        for (int kk = 0; kk < 8; ++kk) {
            aF0[kk] = *(const short8v*)(a0 + kk * 32);
            aF1[kk] = *(const short8v*)(a1 + kk * 32);
            aF2[kk] = *(const short8v*)(a2 + kk * 32);
            aF3[kk] = *(const short8v*)(a3 + kk * 32);
        }
    }
    float thrv[4][4];
    unsigned odeg[4][4];
#pragma unroll
    for (int m = 0; m < 4; ++m)
#pragma unroll
        for (int r = 0; r < 4; ++r) {
            thrv[m][r] = thr[R0 + m * 16 + lg * 4 + r];
            odeg[m][r] = 0;
        }

    uint4 g0, g1, g2, g3;
    STAGE_LOAD(0, 0)
    STAGE_WRITE(sb0)
    __syncthreads();

    f32x4 acc0, acc1, acc2, acc3;
    const int NCT = CW2 / 64;      // 12 col-tiles, 24 units
    for (int u = 0; u < 2 * NCT; ++u) {
        const int ct = u >> 1;
        const int ctN = (u + 1) >> 1, hN = (u + 1) & 1;
        const bool more = (u + 1 < 2 * NCT);
        if (more) STAGE_LOAD(ctN, hN * 256)
        if ((u & 1) == 0) {
            acc0 = {0.f,0.f,0.f,0.f}; acc1 = {0.f,0.f,0.f,0.f};
            acc2 = {0.f,0.f,0.f,0.f}; acc3 = {0.f,0.f,0.f,0.f};
#pragma unroll
            for (int kkl = 0; kkl < 4; ++kkl) {
                short8v bF = *frag_ptr(sb0, w * 16 + l15, kkl, lg);
                acc0 = __builtin_amdgcn_mfma_f32_16x16x32_bf16(aF0[kkl], bF, acc0, 0,0,0);
                acc1 = __builtin_amdgcn_mfma_f32_16x16x32_bf16(aF1[kkl], bF, acc1, 0,0,0);
                acc2 = __builtin_amdgcn_mfma_f32_16x16x32_bf16(aF2[kkl], bF, acc2, 0,0,0);
                acc3 = __builtin_amdgcn_mfma_f32_16x16x32_bf16(aF3[kkl], bF, acc3, 0,0,0);
            }
        } else {
#pragma unroll
            for (int kkl = 0; kkl < 4; ++kkl) {
                short8v bF = *frag_ptr(sb1, w * 16 + l15, kkl, lg);
                acc0 = __builtin_amdgcn_mfma_f32_16x16x32_bf16(aF0[4+kkl], bF, acc0, 0,0,0);
                acc1 = __builtin_amdgcn_mfma_f32_16x16x32_bf16(aF1[4+kkl], bF, acc1, 0,0,0);
                acc2 = __builtin_amdgcn_mfma_f32_16x16x32_bf16(aF2[4+kkl], bF, acc2, 0,0,0);
                acc3 = __builtin_amdgcn_mfma_f32_16x16x32_bf16(aF3[4+kkl], bF, acc3, 0,0,0);
            }
            // epilogue: threshold hits for this 64x64 sub-tile
            const int cg = Cb + ct * 64 + w * 16 + l15;
            unsigned cnt = 0;
            {
                const int rg0 = R0 + lg * 4;
#pragma unroll
                for (int r = 0; r < 4; ++r) {
                    bool h0 = (acc0[r] >= thrv[0][r]) && (cg != rg0 + r);
                    bool h1 = (acc1[r] >= thrv[1][r]) && (cg != rg0 + 16 + r);
                    bool h2 = (acc2[r] >= thrv[2][r]) && (cg != rg0 + 32 + r);
                    bool h3 = (acc3[r] >= thrv[3][r]) && (cg != rg0 + 48 + r);
                    odeg[0][r] += h0; odeg[1][r] += h1;
                    odeg[2][r] += h2; odeg[3][r] += h3;
                    cnt += (unsigned)h0 + (unsigned)h1 + (unsigned)h2 + (unsigned)h3;
                }
            }
            cnt += __shfl_xor(cnt, 16);
            cnt += __shfl_xor(cnt, 32);
            if (lg == 0 && cnt) atomicAdd(&colcnt[ct * 64 + w * 16 + l15], cnt);
        }
        if (more) {
            if (hN) STAGE_WRITE(sb1) else STAGE_WRITE(sb0)
        }
        __syncthreads();
    }

    // out-degree: reduce over the 16 lanes sharing each row set, then global add
#pragma unroll
    for (int off = 1; off < 16; off <<= 1)
#pragma unroll
        for (int m = 0; m < 4; ++m)
#pragma unroll
            for (int r = 0; r < 4; ++r) odeg[m][r] += __shfl_xor(odeg[m][r], off);
    if (l15 == 0) {
#pragma unroll
        for (int m = 0; m < 4; ++m)
#pragma unroll
            for (int r = 0; r < 4; ++r)
                if (odeg[m][r]) atomicAdd(&dd[R0 + m * 16 + lg * 4 + r], odeg[m][r]);
    }
    __syncthreads();
    for (int i = threadIdx.x; i < CW2; i += 256) {
        unsigned c = colcnt[i];
        if (c) atomicAdd(&gg[Cb + i], c);
    }
}

// ---------- 5) wsum = sum_i o*d + g*d - 2o, d = max(o,1)  (integer, determ.) ----------
__global__ void k_wsum(const unsigned* __restrict__ dd, const unsigned* __restrict__ gg,
                       unsigned long long* __restrict__ wsum) {
    const int i = blockIdx.x * 256 + threadIdx.x;
    const unsigned long long o = dd[i];
    const unsigned long long g = gg[i];
    const unsigned long long d = o ? o : 1ull;
    unsigned long long acc = o * d + g * d - 2ull * o;
#pragma unroll
    for (int off = 32; off > 0; off >>= 1) acc += __shfl_xor(acc, off);
    if ((threadIdx.x & 63) == 0 && acc) atomicAdd(wsum, acc);
}

// ---------- 6) finalize ----------
__global__ void k_fin(const unsigned long long* __restrict__ wsum, float* __restrict__ out) {
    out[0] = (float)((double)*wsum * (0.01 / ((double)NR * (double)NR)));
}

extern "C" void kernel_launch(void* const* d_in, const int* in_sizes, int n_in,
                              void* d_out, int out_size, void* d_ws, size_t ws_size,
                              hipStream_t stream) {
    const float* x = (const float*)d_in[0];
    float* out = (float*)d_out;
    char* ws = (char*)d_ws;

    size_t off = 0;
    unsigned short* emb = (unsigned short*)(ws + off); off += (size_t)NR * DIMS * 2;          // 6.29 MB
    float* t9p = (float*)(ws + off);                  off += (size_t)NR * NCH1 * TOPP * 4;    // 3.54 MB
    float* thr = (float*)(ws + off);                  off += (size_t)NR * 4;
    unsigned* dd = (unsigned*)(ws + off);             off += (size_t)NR * 4;
    unsigned* gg = (unsigned*)(ws + off);             off += (size_t)NR * 4;
    unsigned long long* wsum = (unsigned long long*)(ws + off);

    hipMemsetAsync(dd, 0, (size_t)NR * 4, stream);
    hipMemsetAsync(gg, 0, (size_t)NR * 4, stream);
    hipMemsetAsync(wsum, 0, 8, stream);

    k_norm<<<NR / 4, 256, 0, stream>>>(x, emb);
    k_pass1<<<(NR / 64) * NCH1, 256, 0, stream>>>(emb, t9p);
    k_thr<<<NR / 256, 256, 0, stream>>>(t9p, thr);
    k_pass2<<<(NR / 64) * NCH2, 256, 0, stream>>>(emb, thr, dd, gg);
    k_wsum<<<NR / 256, 256, 0, stream>>>(dd, gg, wsum);
    k_fin<<<1, 1, 0, stream>>>(wsum, out);
}

// Round 5
// 336.674 us; speedup vs baseline: 3.6045x; 3.3847x over previous
//
#include <hip/hip_runtime.h>
#include <hip/hip_bf16.h>

#define NR 12288
#define DIMS 256
#define RB 512              // row bytes = DIMS * 2 (bf16)
#define NCH 8
#define CWIDTH (NR / NCH)   // 1536
#define TOPP 9

typedef __attribute__((ext_vector_type(8))) short short8v;
typedef __attribute__((ext_vector_type(4))) float f32x4;

__device__ __forceinline__ unsigned short f2bf(float f) {
    unsigned int u = __float_as_uint(f);
    u += 0x7fffu + ((u >> 16) & 1u);   // round-to-nearest-even
    return (unsigned short)(u >> 16);
}

// Packed ranking key: top 18 bits = sortable float (sign-flipped IEEE), low
// 14 bits = column index (NR=12288 < 16384). Keys are globally UNIQUE, so
// top-9 selection and >=-threshold counting are tie-free by construction.
// Truncating 14 mantissa bits only permutes within-quantum near-ties; since
// each row keeps exactly 9 candidates (o = 8 after diag removal), the final
// wsum is independent of which tie wins.
__device__ __forceinline__ unsigned packkey(float v, int col) {
    unsigned u = __float_as_uint(v);
    u ^= (unsigned)((int)u >> 31) | 0x80000000u;   // monotone: f < g <=> u(f) < u(g)
    return (u & 0xFFFFC000u) | (unsigned)col;
}

// Maintain the 9 largest unique keys. Static indexing only (rule #20);
// unique keys -> exactly one slot matches mn on replace.
__device__ __forceinline__ void top9u(unsigned (&a)[9], unsigned& mn, unsigned key) {
    if (key > mn) {
#pragma unroll
        for (int k = 0; k < 9; ++k) a[k] = (a[k] == mn) ? key : a[k];
        unsigned m = a[0];
#pragma unroll
        for (int k = 1; k < 9; ++k) m = min(m, a[k]);
        mn = m;
    }
}

// ---------- 1) row-normalize fp32 -> bf16, one row per wave ----------
__global__ void k_norm(const float* __restrict__ x, unsigned short* __restrict__ emb) {
    const int wave = threadIdx.x >> 6, lane = threadIdx.x & 63;
    const int row = blockIdx.x * 4 + wave;
    const float4 v = *(const float4*)(x + (size_t)row * DIMS + lane * 4);
    float ss = v.x * v.x + v.y * v.y + v.z * v.z + v.w * v.w;
#pragma unroll
    for (int off = 32; off > 0; off >>= 1) ss += __shfl_xor(ss, off);
    const float inv = 1.0f / fmaxf(sqrtf(ss), 1e-12f);
    ushort4 o;
    o.x = f2bf(v.x * inv); o.y = f2bf(v.y * inv);
    o.z = f2bf(v.z * inv); o.w = f2bf(v.w * inv);
    *(ushort4*)(emb + (size_t)row * DIMS + lane * 4) = o;
}

// Half-K tile in LDS: 64 cols x 128 K = 16 KB. Byte b of the linear tile
// (col = b>>8) is stored at b ^ ((col&7)<<4) so fragment reads (16 lanes,
// same k-slice, 16 consecutive cols) spread across banks (8-round minimum).
__device__ __forceinline__ const short8v* frag_ptr(const char* buf, int col, int kkl, int lg) {
    const int b = (col << 8) + (kkl << 6) + (lg << 4);
    return (const short8v*)(buf + (b ^ ((col & 7) << 4)));
}

#define STAGE_LOAD(CT, HOFF)                                                   \
    {                                                                          \
        const char* p_ = embB + (size_t)(Cb + (CT) * 64 + colA) * RB + (HOFF) + win; \
        g0 = *(const uint4*)(p_);                                              \
        g1 = *(const uint4*)(p_ + 16 * RB);                                    \
        g2 = *(const uint4*)(p_ + 32 * RB);                                    \
        g3 = *(const uint4*)(p_ + 48 * RB);                                    \
    }

#define STAGE_WRITE(SB)                                                        \
    {                                                                          \
        char* d_ = (SB) + colA * 256 + (win ^ swzA);                           \
        *(uint4*)(d_ + 0)     = g0;                                            \
        *(uint4*)(d_ + 4096)  = g1;                                            \
        *(uint4*)(d_ + 8192)  = g2;                                            \
        *(uint4*)(d_ + 12288) = g3;                                            \
    }

// ---------- 2) the ONLY GEMM pass: per-row top-9 (packed keys) per chunk ----
// 64 rows/block, 4 waves x 16 rows; B chunk staged in LDS, double-buffered.
// __launch_bounds__(256,2): VGPR cap 256 -- ~116 live regs, must NOT spill
// (round-4 lesson: spill -> 2.4 GB scratch traffic dominates everything).
__global__ __launch_bounds__(256, 2) void k_pass1(const unsigned short* __restrict__ emb,
                                                  unsigned* __restrict__ t9p) {
    const int bid = blockIdx.x;
    const int chunk = bid & 7, rb = bid >> 3;      // chunk == XCD id (bid%8)
    const int w = threadIdx.x >> 6, lane = threadIdx.x & 63;
    const int l15 = lane & 15, lg = lane >> 4;
    const int R0 = rb * 64 + w * 16;
    const int Cb = chunk * CWIDTH;
    const char* embB = (const char*)emb;
    const int colA = threadIdx.x >> 4;
    const int win = (threadIdx.x & 15) * 16;
    const int swzA = (colA & 7) << 4;

    __shared__ __align__(1024) char sb0[16384];
    __shared__ __align__(1024) char sb1[16384];

    // A fragments: 16 rows x 256 K in registers (one-time scattered load).
    short8v aF[8];
    const unsigned short* ab = emb + (size_t)(R0 + l15) * DIMS + lg * 8;
#pragma unroll
    for (int kk = 0; kk < 8; ++kk) aF[kk] = *(const short8v*)(ab + kk * 32);

    unsigned t9[4][9]; unsigned kmin[4];
#pragma unroll
    for (int r = 0; r < 4; ++r) {
        kmin[r] = 0;
#pragma unroll
        for (int k = 0; k < 9; ++k) t9[r][k] = (unsigned)k;   // unique, below any real key
    }

    uint4 g0, g1, g2, g3;
    STAGE_LOAD(0, 0)
    STAGE_WRITE(sb0)
    __syncthreads();

    f32x4 acc0, acc1, acc2, acc3;
    const int NCT = CWIDTH / 64;   // 24 col-tiles, 48 units (2 K-halves each)
    for (int u = 0; u < 2 * NCT; ++u) {
        const int ct = u >> 1;
        const int ctN = (u + 1) >> 1, hN = (u + 1) & 1;
        const bool more = (u + 1 < 2 * NCT);
        if (more) STAGE_LOAD(ctN, hN * 256)        // issue next-unit loads early
        if ((u & 1) == 0) {
            acc0 = {0.f,0.f,0.f,0.f}; acc1 = {0.f,0.f,0.f,0.f};
            acc2 = {0.f,0.f,0.f,0.f}; acc3 = {0.f,0.f,0.f,0.f};
#pragma unroll
            for (int kkl = 0; kkl < 4; ++kkl) {    // K 0..127 from sb0
                short8v b0 = *frag_ptr(sb0,      l15, kkl, lg);
                short8v b1 = *frag_ptr(sb0, 16 + l15, kkl, lg);
                short8v b2 = *frag_ptr(sb0, 32 + l15, kkl, lg);
                short8v b3 = *frag_ptr(sb0, 48 + l15, kkl, lg);
                acc0 = __builtin_amdgcn_mfma_f32_16x16x32_bf16(aF[kkl], b0, acc0, 0,0,0);
                acc1 = __builtin_amdgcn_mfma_f32_16x16x32_bf16(aF[kkl], b1, acc1, 0,0,0);
                acc2 = __builtin_amdgcn_mfma_f32_16x16x32_bf16(aF[kkl], b2, acc2, 0,0,0);
                acc3 = __builtin_amdgcn_mfma_f32_16x16x32_bf16(aF[kkl], b3, acc3, 0,0,0);
            }
        } else {
#pragma unroll
            for (int kkl = 0; kkl < 4; ++kkl) {    // K 128..255 from sb1
                short8v b0 = *frag_ptr(sb1,      l15, kkl, lg);
                short8v b1 = *frag_ptr(sb1, 16 + l15, kkl, lg);
                short8v b2 = *frag_ptr(sb1, 32 + l15, kkl, lg);
                short8v b3 = *frag_ptr(sb1, 48 + l15, kkl, lg);
                acc0 = __builtin_amdgcn_mfma_f32_16x16x32_bf16(aF[4+kkl], b0, acc0, 0,0,0);
                acc1 = __builtin_amdgcn_mfma_f32_16x16x32_bf16(aF[4+kkl], b1, acc1, 0,0,0);
                acc2 = __builtin_amdgcn_mfma_f32_16x16x32_bf16(aF[4+kkl], b2, acc2, 0,0,0);
                acc3 = __builtin_amdgcn_mfma_f32_16x16x32_bf16(aF[4+kkl], b3, acc3, 0,0,0);
            }
            // C layout (m89): col = l15, row = lg*4 + r. Pack with global col.
            const int c0 = Cb + ct * 64 + l15;
#pragma unroll
            for (int r = 0; r < 4; ++r) {
                top9u(t9[r], kmin[r], packkey(acc0[r], c0));
                top9u(t9[r], kmin[r], packkey(acc1[r], c0 + 16));
                top9u(t9[r], kmin[r], packkey(acc2[r], c0 + 32));
                top9u(t9[r], kmin[r], packkey(acc3[r], c0 + 48));
            }
        }
        if (more) {
            if (hN) STAGE_WRITE(sb1) else STAGE_WRITE(sb0)
        }
        __syncthreads();
    }

    // exact merge across the 16 lanes sharing each row (snapshot-then-insert)
#pragma unroll
    for (int off = 1; off < 16; off <<= 1) {
#pragma unroll
        for (int r = 0; r < 4; ++r) {
            unsigned o[9];
#pragma unroll
            for (int k = 0; k < 9; ++k) o[k] = (unsigned)__shfl_xor((int)t9[r][k], off);
#pragma unroll
            for (int k = 0; k < 9; ++k) top9u(t9[r], kmin[r], o[k]);
        }
    }
    if (l15 == 0) {
#pragma unroll
        for (int r = 0; r < 4; ++r) {
            unsigned* dst = t9p + ((size_t)(R0 + lg * 4 + r) * NCH + chunk) * TOPP;
#pragma unroll
            for (int k = 0; k < 9; ++k) dst[k] = t9[r][k];
        }
    }
}

// ---------- 3) candidate scan: threshold + out/in-degree, no second GEMM ----
// Any j with sim[i,j] >= (9th largest of row i) is in some chunk top-9 of row
// i, so the 72 stored candidates per row suffice. Keys unique -> exactly 9
// candidates >= thr; minus the diagonal -> o_i == 8 for sane inputs.
__global__ void k_scan(const unsigned* __restrict__ t9p,
                       unsigned* __restrict__ dd, unsigned* __restrict__ gg) {
    const int row = blockIdx.x * 256 + threadIdx.x;
    const unsigned* src = t9p + (size_t)row * (NCH * TOPP);
    unsigned a[9]; unsigned mn = 0;
#pragma unroll
    for (int k = 0; k < 9; ++k) a[k] = (unsigned)k;
    for (int c = 0; c < NCH * TOPP; ++c) top9u(a, mn, src[c]);
    const unsigned thr = mn;          // 9th-largest key of the row (incl. diag)
    unsigned o = 0;
    for (int c = 0; c < NCH * TOPP; ++c) {
        const unsigned key = src[c];
        const int col = (int)(key & 16383u);
        if (key >= thr && col != row) { ++o; atomicAdd(&gg[col], 1u); }
    }
    dd[row] = o;
}

// ---------- 4) wsum = sum_i o*d + g*d - 2o, d = max(o,1)  (integer, determ.) ----------
__global__ void k_wsum(const unsigned* __restrict__ dd, const unsigned* __restrict__ gg,
                       unsigned long long* __restrict__ wsum) {
    const int i = blockIdx.x * 256 + threadIdx.x;
    const unsigned long long o = dd[i];
    const unsigned long long g = gg[i];
    const unsigned long long d = o ? o : 1ull;
    unsigned long long acc = o * d + g * d - 2ull * o;
#pragma unroll
    for (int off = 32; off > 0; off >>= 1) acc += __shfl_xor(acc, off);
    if ((threadIdx.x & 63) == 0 && acc) atomicAdd(wsum, acc);
}

// ---------- 5) finalize ----------
__global__ void k_fin(const unsigned long long* __restrict__ wsum, float* __restrict__ out) {
    out[0] = (float)((double)*wsum * (0.01 / ((double)NR * (double)NR)));
}

extern "C" void kernel_launch(void* const* d_in, const int* in_sizes, int n_in,
                              void* d_out, int out_size, void* d_ws, size_t ws_size,
                              hipStream_t stream) {
    const float* x = (const float*)d_in[0];
    float* out = (float*)d_out;
    char* ws = (char*)d_ws;

    size_t off = 0;
    unsigned short* emb = (unsigned short*)(ws + off); off += (size_t)NR * DIMS * 2;        // 6.29 MB
    unsigned* t9p = (unsigned*)(ws + off);            off += (size_t)NR * NCH * TOPP * 4;   // 3.54 MB
    unsigned* dd = (unsigned*)(ws + off);             off += (size_t)NR * 4;
    unsigned* gg = (unsigned*)(ws + off);             off += (size_t)NR * 4;
    unsigned long long* wsum = (unsigned long long*)(ws + off);

    hipMemsetAsync(gg, 0, (size_t)NR * 4, stream);
    hipMemsetAsync(wsum, 0, 8, stream);

    k_norm<<<NR / 4, 256, 0, stream>>>(x, emb);
    k_pass1<<<(NR / 64) * NCH, 256, 0, stream>>>(emb, t9p);
    k_scan<<<NR / 256, 256, 0, stream>>>(t9p, dd, gg);
    k_wsum<<<NR / 256, 256, 0, stream>>>(dd, gg, wsum);
    k_fin<<<1, 1, 0, stream>>>(wsum, out);
}